// Round 4
// baseline (116.521 us; speedup 1.0000x reference)
//
#include <hip/hip_runtime.h>
#include <hip/hip_cooperative_groups.h>

namespace cg = cooperative_groups;

// uvs [B=16, J=16, M=512, D=256] fp32. j<8 = u (k=j), j>=8 = v (k=j-8).
// gate_u[b,k,m] = (dot(u[b,k,m,:], colsum(v[b,k])) > 0); symmetric for v.
//
// Cooperative single-kernel, v half (64 MiB) held IN REGISTERS across grid
// syncs -> v is read from HBM exactly once. Total HBM traffic:
// read u+v once (134 MB) + write outputs (134 MB) = 268 MB, one dispatch.
//
// 256 blocks (1/CU) x 1024 threads (16 waves, 4/SIMD -> HW VGPR cap 128).
// Block (bk, s) owns rows [s*256, s*256+256) of slices u[b,k] and v[b,k].
// Wave w rows [w*16, w*16+16); lane l holds float4 column l of each row.
// Per-thread v storage: 16 x float4 = 64 VGPRs, statically indexed.

#define NBLK 256
#define NTHR 1024

typedef float f32x4 __attribute__((ext_vector_type(4)));

__global__ __launch_bounds__(NTHR, 4) void k_fused(const f32x4* __restrict__ in,
                                                   f32x4* __restrict__ out,
                                                   f32x4* __restrict__ vpart,
                                                   f32x4* __restrict__ upart) {
    cg::grid_group grid = cg::this_grid();
    const int blk = blockIdx.x;
    const int s   = blk & 1;
    const int bk  = blk >> 1;              // [0,128)
    const int b   = bk >> 3, k = bk & 7;
    const int t   = threadIdx.x;
    const int l   = t & 63;
    const int w   = t >> 6;

    const size_t vbase = ((size_t)((b * 16 + 8 + k) * 512) + s * 256 + w * 16) * 64 + l;
    const size_t ubase = ((size_t)((b * 16 + k) * 512) + s * 256 + w * 16) * 64 + l;

    __shared__ f32x4 red[NTHR];            // 16 KiB block-reduce buffer

    // ---- Phase A: v chunk -> registers; block-partial column sum ----
    f32x4 vreg[16];
    f32x4 acc = {0.f, 0.f, 0.f, 0.f};
#pragma unroll
    for (int i = 0; i < 16; ++i) {
        vreg[i] = __builtin_nontemporal_load(in + vbase + (size_t)i * 64);
        acc += vreg[i];
    }
    red[t] = acc;
    __syncthreads();
    if (t < 64) {                          // l == t here
        f32x4 r = {0.f, 0.f, 0.f, 0.f};
#pragma unroll
        for (int q = 0; q < 16; ++q) r += red[q * 64 + t];
        vpart[(size_t)blk * 64 + t] = r;
    }

    grid.sync();

    // ---- Phase B: stream u once; gate vs vsum; accumulate usum partial ----
    const f32x4 vs = vpart[(size_t)(bk * 2 + 0) * 64 + l] +
                     vpart[(size_t)(bk * 2 + 1) * 64 + l];
    f32x4 uacc = {0.f, 0.f, 0.f, 0.f};
#pragma unroll 4
    for (int i = 0; i < 16; ++i) {
        f32x4 uv = __builtin_nontemporal_load(in + ubase + (size_t)i * 64);
        uacc += uv;
        float p = uv.x * vs.x + uv.y * vs.y + uv.z * vs.z + uv.w * vs.w;
#pragma unroll
        for (int off = 32; off; off >>= 1) p += __shfl_xor(p, off, 64);
        const float g = (p > 0.f) ? 1.f : 0.f;
        __builtin_nontemporal_store(uv * g, out + ubase + (size_t)i * 64);
    }
    __syncthreads();
    red[t] = uacc;
    __syncthreads();
    if (t < 64) {
        f32x4 r = {0.f, 0.f, 0.f, 0.f};
#pragma unroll
        for (int q = 0; q < 16; ++q) r += red[q * 64 + t];
        upart[(size_t)blk * 64 + t] = r;
    }

    grid.sync();

    // ---- Phase C: gate register-resident v; store (no v re-read) ----
    const f32x4 us = upart[(size_t)(bk * 2 + 0) * 64 + l] +
                     upart[(size_t)(bk * 2 + 1) * 64 + l];
#pragma unroll
    for (int i = 0; i < 16; ++i) {
        float p = vreg[i].x * us.x + vreg[i].y * us.y +
                  vreg[i].z * us.z + vreg[i].w * us.w;
#pragma unroll
        for (int off = 32; off; off >>= 1) p += __shfl_xor(p, off, 64);
        const float g = (p > 0.f) ? 1.f : 0.f;
        __builtin_nontemporal_store(vreg[i] * g, out + vbase + (size_t)i * 64);
    }
}

extern "C" void kernel_launch(void* const* d_in, const int* in_sizes, int n_in,
                              void* d_out, int out_size, void* d_ws, size_t ws_size,
                              hipStream_t stream) {
    const f32x4* in  = (const f32x4*)d_in[0];
    f32x4*       out = (f32x4*)d_out;
    // ws: vpart 256 KiB @ 0, upart 256 KiB @ 256 KiB. Fully written each call
    // before being read (replay-safe; no atomics anywhere).
    f32x4* vpart = (f32x4*)d_ws;
    f32x4* upart = (f32x4*)((char*)d_ws + (256u << 10));

    void* args[] = { (void*)&in, (void*)&out, (void*)&vpart, (void*)&upart };
    hipLaunchCooperativeKernel((void*)k_fused, dim3(NBLK), dim3(NTHR),
                               args, 0, stream);
}